// Round 6
// baseline (6399.420 us; speedup 1.0000x reference)
//
#include <hip/hip_runtime.h>
#include <hip/hip_fp16.h>
#include <math.h>

// Echo-state network: sequential scan with dense 2048x2048 matvec per step.
// R26 -- sc0 (own-L2) polling with sticky agent-scope escalation.
//
// R25 (passed, 6.21ms total, NEW BEST): 8-chunk + f16-only h transport.
// Round 2.81us = consume ~1.4us + transport ~1.4us. Transport still pays
// ~700cy LLC RT per poll sweep (agent loads bypass L1+L2).
//
// R26 cuts poll latency using what the 8-chunk geometry built: chunk=blk&7
// puts a chunk's 32 blocks on one XCD (blk%8 round-robin) sharing one L2.
// sc0-only loads (bypass L1, read own L2) should see same-XCD agent stores
// at ~250cy. R23's hang-prone parts are removed BY CONSTRUCTION:
//  - Stores remain AGENT-scope (R25-proven): LLC always fresh; warm-up
//    overwrite ordering + out_kernel correctness unchanged; no probe, no
//    getreg, no scratch ring.
//  - Polls: up to 32 sc0 sweeps, then STICKY per-thread escalation to the
//    R25 agent poll. Stale-positive impossible: each states[] address holds
//    at most ONE value in my parity class (my chunk writes each g once; the
//    only other writer -- a neighbor chunk's warm-up -- has the opposite
//    bias tag), so any sc0 hit passing the parity check is the true value.
//    If mapping or L2-update assumptions fail: one-time 32-sweep cost,
//    then exact R25 behavior. No hang path.
//
// Single new construct: poll4_sc0 asm (4x global_load_dword sc0 + one
// s_waitcnt vmcnt(0)); everything else byte-identical to R25.
//
// Carried from R25/R24/R22: 8 chunks x 32 blocks x 512 thr; rows 0..3/wave
// W fp32 in regs (PIN4, AGPR placement), rows 4..7/wave W f16 in LDS;
// f16-only h dbuf in LDS; fdot2 consume; twred bias-fold post-butterfly;
// C0LEN=2104/CLEN=2040/WUP=64 -> NROUND=2104; parity bias-tags 2/6;
// in-loop x load; publish + ONE barrier; fold+butterfly reduce; tanh;
// agent store; fc1/fc2 collapse: out = states_b @ Mt + (c2b - bias_t*rm).

#define SS 16384
#define II 64
#define RR 2048
#define HH 128
#define OO 50
#define OP 64          // padded output dim
#define NROUND 2104    // rounds per chunk (uniform)
#define C0LEN 2104     // chunk 0 output length
#define CLEN 2040      // chunks 1-7 output length
#define WUP 64         // warm-up steps for chunks 1-7
#define NBLK 256
#define NTHR 512
#define TT 16          // timesteps per block in out_kernel
#define SC0_TRIES 32   // sc0 sweeps before sticky agent escalation

// W f16 rows (128KB) + h f16 dbuf (8KB)
#define SMEM_BYTES (32 * RR * 2 + 2 * RR * 2)   // 139264

static const size_t STATES_BYTES = (size_t)SS * RR * 4;        // 134217728
static const size_t MT_OFF  = STATES_BYTES;
static const size_t C2B_OFF = MT_OFF + (size_t)RR * OP * 4;    // +524288
static const size_t RM_OFF  = C2B_OFF + 256;
static const size_t RS_OFF  = RM_OFF + 256;
static const size_t WS_NEED = RS_OFF + 512 + 256;

typedef _Float16 h2v __attribute__((ext_vector_type(2)));

// Opaque register pin for LOOP-INVARIANT values (W fragments) only.
// NEVER on in-loop load results (forces a waitcnt at the pin site -- R6/R15).
#define PIN4(q) asm volatile("" : "+v"((q).x), "+v"((q).y), "+v"((q).z), "+v"((q).w))

// Batched 4x sc0 poll: bypass L1, read the XCD-shared L2. One vmcnt(0)
// drains all four (plus any outstanding x load -- R16 ordering).
__device__ __forceinline__ void poll4_sc0(const float* p0, const float* p1,
                                          const float* p2, const float* p3,
                                          float& v0, float& v1,
                                          float& v2, float& v3)
{
    asm volatile(
        "global_load_dword %0, %4, off sc0\n\t"
        "global_load_dword %1, %5, off sc0\n\t"
        "global_load_dword %2, %6, off sc0\n\t"
        "global_load_dword %3, %7, off sc0\n\t"
        "s_waitcnt vmcnt(0)"
        : "=&v"(v0), "=&v"(v1), "=&v"(v2), "=&v"(v3)
        : "v"(p0), "v"(p1), "v"(p2), "v"(p3)
        : "memory");
}

// ---------------------------------------------------------------------------
// Persistent chunked scan. chunk = blk&7, brow = blk>>3.
// Wave w owns rows R0 = brow*64 + w*8 .. R0+7.
//   rows R0+0..3: W fp32 in registers, lane l holds cols {4l+j+256m}.
//   rows R0+4..7: W f16 in LDS, same column mapping, wave-private.
// h transport: f16 mirror only, [2][RR] dbuf.
// ---------------------------------------------------------------------------
__global__ __launch_bounds__(NTHR, 2)
void scan_kernel(const float* __restrict__ x,
                 const float* __restrict__ Win,
                 const float* __restrict__ W,
                 float* __restrict__ states)
{
    const int tid   = threadIdx.x;
    const int blk   = blockIdx.x;
    const int wave  = tid >> 6;             // 0..7
    const int lane  = tid & 63;
    const int chunk = blk & 7;
    const int brow  = blk >> 3;             // 0..31
    const int R0    = brow * 64 + wave * 8;

    const float bias = (chunk & 1) ? 6.0f : 2.0f;
    const int g0 = CLEN * chunk;            // 0 for chunk 0; warm-up start else

    extern __shared__ char smem_raw[];
    uint2*    wl2 = (uint2*)smem_raw;                       // 32 x 512 uint2
    _Float16* h16 = (_Float16*)(smem_raw + 32 * RR * 2);    // [2][RR]

    // --- Register W: rows 0..3, byte-identical to proven baseline ---
    float4 wq[4][8];
#pragma unroll
    for (int r = 0; r < 4; ++r)
#pragma unroll
        for (int m = 0; m < 8; ++m) {
            wq[r][m] = *(const float4*)&W[(size_t)(R0 + r) * RR + 4 * lane + 256 * m];
            PIN4(wq[r][m]);
        }

    // Per-row bias-fold partials (reg rows: exact fp32 values)
    float twp[8];
#pragma unroll
    for (int r = 0; r < 4; ++r) {
        float s = 0.f;
#pragma unroll
        for (int m = 0; m < 8; ++m)
            s += wq[r][m].x + wq[r][m].y + wq[r][m].z + wq[r][m].w;
        twp[r] = s;
    }

    // --- LDS W: rows 4..7, packed f16, wave-private (no barrier needed) ---
    const int wrow = wave * 4;              // my first LDS row slot
#pragma unroll
    for (int rr = 0; rr < 4; ++rr) {
        float s = 0.f;
#pragma unroll
        for (int m = 0; m < 8; ++m) {
            const float4 wv = *(const float4*)&W[(size_t)(R0 + 4 + rr) * RR + 4 * lane + 256 * m];
            const __half h0 = __float2half_rn(wv.x);
            const __half h1 = __float2half_rn(wv.y);
            const __half h2 = __float2half_rn(wv.z);
            const __half h3 = __float2half_rn(wv.w);
            uint2 p;
            p.x = __builtin_bit_cast(unsigned int, __halves2half2(h0, h1));
            p.y = __builtin_bit_cast(unsigned int, __halves2half2(h2, h3));
            wl2[(size_t)(wrow + rr) * 512 + lane + 64 * m] = p;
            // tw from the ROUNDED values (what the dot product will use)
            s += __half2float(h0) + __half2float(h1)
               + __half2float(h2) + __half2float(h3);
        }
        twp[4 + rr] = s;
    }

    // Pre-reduce tw across lanes with the SAME fold+butterfly as the main
    // loop: after this, every lane holds bias * rowsum(W[R0+(lane&7)]).
    float twred;
    {
        const float u01 = ((lane & 1) ? twp[1] : twp[0])
                        + __shfl_xor((lane & 1) ? twp[0] : twp[1], 1, 64);
        const float u23 = ((lane & 1) ? twp[3] : twp[2])
                        + __shfl_xor((lane & 1) ? twp[2] : twp[3], 1, 64);
        const float u45 = ((lane & 1) ? twp[5] : twp[4])
                        + __shfl_xor((lane & 1) ? twp[4] : twp[5], 1, 64);
        const float u67 = ((lane & 1) ? twp[7] : twp[6])
                        + __shfl_xor((lane & 1) ? twp[6] : twp[7], 1, 64);
        const float v03 = ((lane & 2) ? u23 : u01)
                        + __shfl_xor((lane & 2) ? u01 : u23, 2, 64);
        const float v47 = ((lane & 2) ? u67 : u45)
                        + __shfl_xor((lane & 2) ? u45 : u67, 2, 64);
        float a = ((lane & 4) ? v47 : v03)
                + __shfl_xor((lane & 4) ? v03 : v47, 4, 64);
#pragma unroll
        for (int off = 8; off <= 32; off <<= 1)
            a += __shfl_xor(a, off, 64);
        twred = bias * a;
    }

    // Input projection fragments
    float win[8];
#pragma unroll
    for (int r = 0; r < 8; ++r)
        win[r] = Win[(size_t)(R0 + r) * II + lane];

    float hold = 0.f;               // lane tracks row R0 + (lane&7)
    int   mode = 0;                 // 0 = sc0 fast poll, 1 = agent (sticky)

    for (int j = 0; j < NROUND; ++j) {
        const int g = g0 + j;
        const float xv = x[(size_t)g * II + lane];  // in-loop: drains with poll
        float acc[8];
#pragma unroll
        for (int r = 0; r < 8; ++r) acc[r] = win[r] * xv;

        if (j > 0) {
            const float* hp = states + (size_t)(g - 1) * RR;
            _Float16* sh = h16 + ((j - 1) & 1) * RR;
            float v0, v1, v2, v3;

            if (mode == 0) {
                // Fast path: own-L2 polling. Parity check makes any hit
                // that passes necessarily the true value (see header).
                poll4_sc0(hp + tid, hp + tid + 512,
                          hp + tid + 1024, hp + tid + 1536, v0, v1, v2, v3);
                int tries = 0;
                for (;;) {
                    const bool r0 = fabsf(v0 - bias) <= 1.25f;
                    const bool r1 = fabsf(v1 - bias) <= 1.25f;
                    const bool r2 = fabsf(v2 - bias) <= 1.25f;
                    const bool r3 = fabsf(v3 - bias) <= 1.25f;
                    if (r0 && r1 && r2 && r3) break;
                    if (++tries > SC0_TRIES) { mode = 1; break; }
                    poll4_sc0(hp + tid, hp + tid + 512,
                              hp + tid + 1024, hp + tid + 1536, v0, v1, v2, v3);
                }
            }
            if (mode == 1) {
                // Escalated path: R25-verbatim agent-scope poll (LLC).
                v0 = __hip_atomic_load(hp + tid,
                                       __ATOMIC_RELAXED, __HIP_MEMORY_SCOPE_AGENT);
                v1 = __hip_atomic_load(hp + tid + 512,
                                       __ATOMIC_RELAXED, __HIP_MEMORY_SCOPE_AGENT);
                v2 = __hip_atomic_load(hp + tid + 1024,
                                       __ATOMIC_RELAXED, __HIP_MEMORY_SCOPE_AGENT);
                v3 = __hip_atomic_load(hp + tid + 1536,
                                       __ATOMIC_RELAXED, __HIP_MEMORY_SCOPE_AGENT);
                for (;;) {
                    const bool r0 = fabsf(v0 - bias) <= 1.25f;
                    const bool r1 = fabsf(v1 - bias) <= 1.25f;
                    const bool r2 = fabsf(v2 - bias) <= 1.25f;
                    const bool r3 = fabsf(v3 - bias) <= 1.25f;
                    if (r0 && r1 && r2 && r3) break;
                    if (!r0) v0 = __hip_atomic_load(hp + tid,
                                    __ATOMIC_RELAXED, __HIP_MEMORY_SCOPE_AGENT);
                    if (!r1) v1 = __hip_atomic_load(hp + tid + 512,
                                    __ATOMIC_RELAXED, __HIP_MEMORY_SCOPE_AGENT);
                    if (!r2) v2 = __hip_atomic_load(hp + tid + 1024,
                                    __ATOMIC_RELAXED, __HIP_MEMORY_SCOPE_AGENT);
                    if (!r3) v3 = __hip_atomic_load(hp + tid + 1536,
                                    __ATOMIC_RELAXED, __HIP_MEMORY_SCOPE_AGENT);
                }
            }
            // Publish f16-rounded biased h only (4 cvt + 4 ds_write_b16).
            sh[tid]        = (_Float16)v0;
            sh[tid + 512]  = (_Float16)v1;
            sh[tid + 1024] = (_Float16)v2;
            sh[tid + 1536] = (_Float16)v3;
            __syncthreads();           // the ONLY barrier per round

            // Consume: 8x ds_read_b64 (h f16) + 32x ds_read_b64 (W f16).
            // Rows 0..3: cvt h->f32 (4/m) vs fp32 register W.
            // Rows 4..7: v_dot2_f32_f16 vs LDS f16 W.
            const uint2* sq16 = (const uint2*)sh;
#pragma unroll
            for (int m = 0; m < 8; ++m) {
                const uint2 qh = sq16[lane + 64 * m];
                const h2v qlo = __builtin_bit_cast(h2v, qh.x);
                const h2v qhi = __builtin_bit_cast(h2v, qh.y);
                const float qx = (float)qlo[0];
                const float qy = (float)qlo[1];
                const float qz = (float)qhi[0];
                const float qw = (float)qhi[1];
                acc[0] += wq[0][m].x * qx + wq[0][m].y * qy
                        + wq[0][m].z * qz + wq[0][m].w * qw;
                acc[1] += wq[1][m].x * qx + wq[1][m].y * qy
                        + wq[1][m].z * qz + wq[1][m].w * qw;
                acc[2] += wq[2][m].x * qx + wq[2][m].y * qy
                        + wq[2][m].z * qz + wq[2][m].w * qw;
                acc[3] += wq[3][m].x * qx + wq[3][m].y * qy
                        + wq[3][m].z * qz + wq[3][m].w * qw;
#pragma unroll
                for (int rr = 0; rr < 4; ++rr) {
                    const uint2 wp = wl2[(size_t)(wrow + rr) * 512 + lane + 64 * m];
                    acc[4 + rr] = __builtin_amdgcn_fdot2(
                        __builtin_bit_cast(h2v, wp.x), qlo, acc[4 + rr], false);
                    acc[4 + rr] = __builtin_amdgcn_fdot2(
                        __builtin_bit_cast(h2v, wp.y), qhi, acc[4 + rr], false);
                }
            }
        }

        // Reduce 8 rows: 3 fold stages + 3-level butterfly (10 shfls).
        {
            const float u01 = ((lane & 1) ? acc[1] : acc[0])
                            + __shfl_xor((lane & 1) ? acc[0] : acc[1], 1, 64);
            const float u23 = ((lane & 1) ? acc[3] : acc[2])
                            + __shfl_xor((lane & 1) ? acc[2] : acc[3], 1, 64);
            const float u45 = ((lane & 1) ? acc[5] : acc[4])
                            + __shfl_xor((lane & 1) ? acc[4] : acc[5], 1, 64);
            const float u67 = ((lane & 1) ? acc[7] : acc[6])
                            + __shfl_xor((lane & 1) ? acc[6] : acc[7], 1, 64);
            const float v03 = ((lane & 2) ? u23 : u01)
                            + __shfl_xor((lane & 2) ? u01 : u23, 2, 64);
            const float v47 = ((lane & 2) ? u67 : u45)
                            + __shfl_xor((lane & 2) ? u45 : u67, 2, 64);
            float a = ((lane & 4) ? v47 : v03)
                    + __shfl_xor((lane & 4) ? v03 : v47, 4, 64);
#pragma unroll
            for (int off = 8; off <= 32; off <<= 1)
                a += __shfl_xor(a, off, 64);
            // Bias-fold correction (only when biased h was consumed)
            if (j > 0) a -= twred;
            // tanh + leaky update for row R0 + (lane&7)
            float u = fminf(fmaxf(a, -20.f), 20.f);
            const float e  = __expf(2.f * u);
            const float th = (e - 1.f) / (e + 1.f);
            const float hn = 0.5f * hold + 0.5f * th;
            hold = hn;
            if (lane < 8)
                __hip_atomic_store(&states[(size_t)g * RR + R0 + lane], hn + bias,
                                   __ATOMIC_RELAXED, __HIP_MEMORY_SCOPE_AGENT);
        }
    }
}

// ---------------------------------------------------------------------------
// rowsum of fc1_w rows: rs[h] = sum_r fc1_w[h][r]
// ---------------------------------------------------------------------------
__global__ void k_rowsum(const float* __restrict__ fc1w, float* __restrict__ rs)
{
    const int h = blockIdx.x;
    const int tid = threadIdx.x;
    float a = 0.f;
    for (int r = tid; r < RR; r += 256) a += fc1w[(size_t)h * RR + r];
#pragma unroll
    for (int off = 1; off <= 32; off <<= 1) a += __shfl_xor(a, off, 64);
    __shared__ float red[4];
    if ((tid & 63) == 0) red[tid >> 6] = a;
    __syncthreads();
    if (tid == 0) rs[h] = red[0] + red[1] + red[2] + red[3];
}

// ---------------------------------------------------------------------------
// Mt[r][o] = sum_h fc2_w[o][h] * fc1_w[h][r]   (o padded to 64, zeros)
// ---------------------------------------------------------------------------
__global__ void k_mt(const float* __restrict__ fc1w,
                     const float* __restrict__ fc2w,
                     float* __restrict__ Mt)
{
    __shared__ float w2[OO][HH + 1];
    const int o = threadIdx.x;         // 64
    const int r = blockIdx.x;          // 2048
    for (int i = o; i < OO * HH; i += 64) w2[i / HH][i % HH] = fc2w[i];
    __syncthreads();
    float a = 0.f;
    if (o < OO) {
        for (int h = 0; h < HH; ++h)
            a += w2[o][h] * fc1w[(size_t)h * RR + r];
    }
    Mt[r * OP + o] = a;
}

// ---------------------------------------------------------------------------
// c2b[o] = fc2_b[o] + sum_h fc2_w[o][h]*fc1_b[h];  rm[o] = sum_h fc2w*rs[h]
// ---------------------------------------------------------------------------
__global__ void k_cc(const float* __restrict__ fc2w,
                     const float* __restrict__ fc2b,
                     const float* __restrict__ fc1b,
                     const float* __restrict__ rs,
                     float* __restrict__ c2b,
                     float* __restrict__ rm)
{
    const int o = threadIdx.x;  // 64
    float a = 0.f, b = 0.f;
    if (o < OO) {
        for (int h = 0; h < HH; ++h) {
            a += fc2w[o * HH + h] * fc1b[h];
            b += fc2w[o * HH + h] * rs[h];
        }
        a += fc2b[o];
    }
    c2b[o] = a;
    rm[o]  = b;
}

// ---------------------------------------------------------------------------
// out[t][o] = sum_r Mt[r][o] * states_biased[t][r] + c2b[o] - bias_t*rm[o]
// Chunk boundaries (2104 + 2040k) are NOT %16-aligned -> bias per element.
// ---------------------------------------------------------------------------
__global__ __launch_bounds__(256)
void out_kernel(const float* __restrict__ sb,
                const float* __restrict__ Mt,
                const float* __restrict__ c2b,
                const float* __restrict__ rm,
                float* __restrict__ out)
{
    const int tid = threadIdx.x;
    const int o   = tid & 63;
    const int tl  = tid >> 6;          // 0..3
    const int t0  = blockIdx.x * TT;
    float acc[4] = {0.f, 0.f, 0.f, 0.f};
    const float* s0 = sb + (size_t)t0 * RR;

    for (int r = 0; r < RR; r += 4) {
        float4 sv0 = *(const float4*)(s0 + (size_t)(tl + 0)  * RR + r);
        float4 sv1 = *(const float4*)(s0 + (size_t)(tl + 4)  * RR + r);
        float4 sv2 = *(const float4*)(s0 + (size_t)(tl + 8)  * RR + r);
        float4 sv3 = *(const float4*)(s0 + (size_t)(tl + 12) * RR + r);
        float m0 = Mt[(r + 0) * OP + o];
        float m1 = Mt[(r + 1) * OP + o];
        float m2 = Mt[(r + 2) * OP + o];
        float m3 = Mt[(r + 3) * OP + o];
        acc[0] += m0 * sv0.x + m1 * sv0.y + m2 * sv0.z + m3 * sv0.w;
        acc[1] += m0 * sv1.x + m1 * sv1.y + m2 * sv1.z + m3 * sv1.w;
        acc[2] += m0 * sv2.x + m1 * sv2.y + m2 * sv2.z + m3 * sv2.w;
        acc[3] += m0 * sv3.x + m1 * sv3.y + m2 * sv3.z + m3 * sv3.w;
    }
    if (o < OO) {
        const float cb = c2b[o];
        const float rv = rm[o];
#pragma unroll
        for (int m = 0; m < 4; ++m) {
            const int t = t0 + tl + 4 * m;
            const int ch = (t < C0LEN) ? 0 : (1 + (t - C0LEN) / CLEN);
            const float bias = (ch & 1) ? 6.0f : 2.0f;
            out[(size_t)t * OO + o] = acc[m] + cb - bias * rv;
        }
    }
}

extern "C" void kernel_launch(void* const* d_in, const int* in_sizes, int n_in,
                              void* d_out, int out_size, void* d_ws, size_t ws_size,
                              hipStream_t stream)
{
    const float* x    = (const float*)d_in[0];
    const float* Win  = (const float*)d_in[1];
    const float* W    = (const float*)d_in[2];
    const float* fc1w = (const float*)d_in[3];
    const float* fc1b = (const float*)d_in[4];
    const float* fc2w = (const float*)d_in[5];
    const float* fc2b = (const float*)d_in[6];
    float* out = (float*)d_out;

    if (ws_size < WS_NEED) return;

    char*  ws     = (char*)d_ws;
    float* states = (float*)ws;
    float* Mt     = (float*)(ws + MT_OFF);
    float* c2b    = (float*)(ws + C2B_OFF);
    float* rm     = (float*)(ws + RM_OFF);
    float* rs     = (float*)(ws + RS_OFF);

    // Raise the dynamic-LDS cap once (not a stream op; graph-capture safe).
    static bool attr_done = false;
    if (!attr_done) {
        hipFuncSetAttribute(reinterpret_cast<const void*>(scan_kernel),
                            hipFuncAttributeMaxDynamicSharedMemorySize,
                            SMEM_BYTES);
        attr_done = true;
    }

    // Sentinel init: 0.0f is outside both bias ranges -> "not ready".
    hipMemsetAsync(states, 0, STATES_BYTES, stream);

    k_rowsum<<<HH, 256, 0, stream>>>(fc1w, rs);
    k_mt<<<RR, 64, 0, stream>>>(fc1w, fc2w, Mt);
    k_cc<<<1, 64, 0, stream>>>(fc2w, fc2b, fc1b, rs, c2b, rm);

    scan_kernel<<<NBLK, NTHR, SMEM_BYTES, stream>>>(x, Win, W, states);

    out_kernel<<<SS / TT, 256, 0, stream>>>(states, Mt, c2b, rm, out);
}

// Round 7
// 3930.714 us; speedup vs baseline: 1.6281x; 1.6281x over previous
//
#include <hip/hip_runtime.h>
#include <hip/hip_fp16.h>
#include <math.h>

// Echo-state network: sequential scan with dense 2048x2048 matvec per step.
// R27 -- R25 transport (sc0 reverted) + all-f16 consume: rows 0..3 W packed
// f16 in 64 VGPRs, consumed via v_dot2_f32_f16 like rows 4..7.
//
// R26 post-mortem (passed, scan 6232 vs R25's 5908): sc0 polling REGRESSED.
// Threads stayed in sc0 mode (else perf would equal R25) but agent stores
// update LLC, not the consumer XCD's L2 -- every sc0 poll misses local L2
// and fetches from LLC anyway, plus L2-lookup overhead and the batched
// all-4 reload per sweep. Intra-XCD transport is CLOSED; transport reverted
// to R25 verbatim (agent-scope selective-reload poll).
//
// R27 attacks the next-largest term, consume VALU (2160cy of the 6744cy
// round): rows 0..3 still cost 20 VALU/m (4 cvt + 16 fma) vs rows 4..7's
// 8 fdot2/m. Pack rows 0..3 W as f16 (4 rows x 32 cols = 64 dwords, PIN4)
// and consume via fdot2: per-m VALU 28 -> 16 (-35% round VALU). This is
// R21's layout at HALF the footprint: 64 pinned dwords + ~120 live ~ 184
// <= 256-reg budget @ 2 waves/SIMD -- the R19/R21 spill trap should not
// fire; FETCH_SIZE is the tripwire (GB-scale = spill = revert).
// Numerics: same proven class as R24/R25 (f16 W, f16 h, f32 accum, tw from
// ROUNDED values) -- rows 0..3 join the path that passes bit-identical.
//
// Carried from R25: 8 chunks x 32 blocks x 512 thr; rows 4..7/wave W f16 in
// LDS (wave-private); f16-only h dbuf in LDS; twred bias-fold post-
// butterfly; C0LEN=2104/CLEN=2040/WUP=64 -> NROUND=2104; parity bias-tags
// 2/6; in-loop x load; block-coop agent poll + straggler retry; publish +
// ONE barrier; fold+butterfly reduce; tanh; agent store; fc1/fc2 collapse:
// out = states_biased @ Mt + (c2b - bias_t * rm).

#define SS 16384
#define II 64
#define RR 2048
#define HH 128
#define OO 50
#define OP 64          // padded output dim
#define NROUND 2104    // rounds per chunk (uniform)
#define C0LEN 2104     // chunk 0 output length
#define CLEN 2040      // chunks 1-7 output length
#define WUP 64         // warm-up steps for chunks 1-7
#define NBLK 256
#define NTHR 512
#define TT 16          // timesteps per block in out_kernel

// W f16 rows (128KB) + h f16 dbuf (8KB)
#define SMEM_BYTES (32 * RR * 2 + 2 * RR * 2)   // 139264

static const size_t STATES_BYTES = (size_t)SS * RR * 4;        // 134217728
static const size_t MT_OFF  = STATES_BYTES;
static const size_t C2B_OFF = MT_OFF + (size_t)RR * OP * 4;    // +524288
static const size_t RM_OFF  = C2B_OFF + 256;
static const size_t RS_OFF  = RM_OFF + 256;
static const size_t WS_NEED = RS_OFF + 512 + 256;

typedef _Float16 h2v __attribute__((ext_vector_type(2)));

// Opaque register pin for LOOP-INVARIANT values (W fragments) only.
// NEVER on in-loop load results (forces a waitcnt at the pin site -- R6/R15).
#define PIN4(q) asm volatile("" : "+v"((q).x), "+v"((q).y), "+v"((q).z), "+v"((q).w))

// ---------------------------------------------------------------------------
// Persistent chunked scan. chunk = blk&7, brow = blk>>3.
// Wave w owns rows R0 = brow*64 + w*8 .. R0+7.
//   rows R0+0..3: W f16-packed in 64 VGPRs; lane l holds cols {4l+j+256m}.
//     wq16[r][k]: {pack(c0,c1)@m=2k, pack(c2,c3)@m=2k,
//                  pack(c0,c1)@m=2k+1, pack(c2,c3)@m=2k+1}
//   rows R0+4..7: W f16 in LDS, same column mapping, wave-private.
// h transport: f16 mirror only, [2][RR] dbuf.
// ---------------------------------------------------------------------------
__global__ __launch_bounds__(NTHR, 2)
void scan_kernel(const float* __restrict__ x,
                 const float* __restrict__ Win,
                 const float* __restrict__ W,
                 float* __restrict__ states)
{
    const int tid   = threadIdx.x;
    const int blk   = blockIdx.x;
    const int wave  = tid >> 6;             // 0..7
    const int lane  = tid & 63;
    const int chunk = blk & 7;
    const int brow  = blk >> 3;             // 0..31
    const int R0    = brow * 64 + wave * 8;

    const float bias = (chunk & 1) ? 6.0f : 2.0f;
    const int g0 = CLEN * chunk;            // 0 for chunk 0; warm-up start else

    extern __shared__ char smem_raw[];
    uint2*    wl2 = (uint2*)smem_raw;                       // 32 x 512 uint2
    _Float16* h16 = (_Float16*)(smem_raw + 32 * RR * 2);    // [2][RR]

    // --- Register W: rows 0..3, packed f16 (64 dwords), pinned ---
    float4 wq16[4][4];
    float twp[8];
#pragma unroll
    for (int r = 0; r < 4; ++r) {
        float s = 0.f;
#pragma unroll
        for (int k = 0; k < 4; ++k) {
            const size_t base = (size_t)(R0 + r) * RR + 4 * lane;
            const float4 we = *(const float4*)&W[base + 256 * (2 * k)];
            const float4 wo = *(const float4*)&W[base + 256 * (2 * k + 1)];
            const __half e0 = __float2half_rn(we.x), e1 = __float2half_rn(we.y);
            const __half e2 = __float2half_rn(we.z), e3 = __float2half_rn(we.w);
            const __half o0 = __float2half_rn(wo.x), o1 = __float2half_rn(wo.y);
            const __half o2 = __float2half_rn(wo.z), o3 = __float2half_rn(wo.w);
            wq16[r][k].x = __builtin_bit_cast(float, __halves2half2(e0, e1));
            wq16[r][k].y = __builtin_bit_cast(float, __halves2half2(e2, e3));
            wq16[r][k].z = __builtin_bit_cast(float, __halves2half2(o0, o1));
            wq16[r][k].w = __builtin_bit_cast(float, __halves2half2(o2, o3));
            PIN4(wq16[r][k]);
            // tw from the ROUNDED values (what the dot product will use)
            s += __half2float(e0) + __half2float(e1)
               + __half2float(e2) + __half2float(e3)
               + __half2float(o0) + __half2float(o1)
               + __half2float(o2) + __half2float(o3);
        }
        twp[r] = s;
    }

    // --- LDS W: rows 4..7, packed f16, wave-private (no barrier needed) ---
    const int wrow = wave * 4;              // my first LDS row slot
#pragma unroll
    for (int rr = 0; rr < 4; ++rr) {
        float s = 0.f;
#pragma unroll
        for (int m = 0; m < 8; ++m) {
            const float4 wv = *(const float4*)&W[(size_t)(R0 + 4 + rr) * RR + 4 * lane + 256 * m];
            const __half h0 = __float2half_rn(wv.x);
            const __half h1 = __float2half_rn(wv.y);
            const __half h2 = __float2half_rn(wv.z);
            const __half h3 = __float2half_rn(wv.w);
            uint2 p;
            p.x = __builtin_bit_cast(unsigned int, __halves2half2(h0, h1));
            p.y = __builtin_bit_cast(unsigned int, __halves2half2(h2, h3));
            wl2[(size_t)(wrow + rr) * 512 + lane + 64 * m] = p;
            s += __half2float(h0) + __half2float(h1)
               + __half2float(h2) + __half2float(h3);
        }
        twp[4 + rr] = s;
    }

    // Pre-reduce tw across lanes with the SAME fold+butterfly as the main
    // loop: after this, every lane holds bias * rowsum(W[R0+(lane&7)]).
    float twred;
    {
        const float u01 = ((lane & 1) ? twp[1] : twp[0])
                        + __shfl_xor((lane & 1) ? twp[0] : twp[1], 1, 64);
        const float u23 = ((lane & 1) ? twp[3] : twp[2])
                        + __shfl_xor((lane & 1) ? twp[2] : twp[3], 1, 64);
        const float u45 = ((lane & 1) ? twp[5] : twp[4])
                        + __shfl_xor((lane & 1) ? twp[4] : twp[5], 1, 64);
        const float u67 = ((lane & 1) ? twp[7] : twp[6])
                        + __shfl_xor((lane & 1) ? twp[6] : twp[7], 1, 64);
        const float v03 = ((lane & 2) ? u23 : u01)
                        + __shfl_xor((lane & 2) ? u01 : u23, 2, 64);
        const float v47 = ((lane & 2) ? u67 : u45)
                        + __shfl_xor((lane & 2) ? u45 : u67, 2, 64);
        float a = ((lane & 4) ? v47 : v03)
                + __shfl_xor((lane & 4) ? v03 : v47, 4, 64);
#pragma unroll
        for (int off = 8; off <= 32; off <<= 1)
            a += __shfl_xor(a, off, 64);
        twred = bias * a;
    }

    // Input projection fragments
    float win[8];
#pragma unroll
    for (int r = 0; r < 8; ++r)
        win[r] = Win[(size_t)(R0 + r) * II + lane];

    float hold = 0.f;               // lane tracks row R0 + (lane&7)

    for (int j = 0; j < NROUND; ++j) {
        const int g = g0 + j;
        const float xv = x[(size_t)g * II + lane];  // in-loop: drains with poll
        float acc[8];
#pragma unroll
        for (int r = 0; r < 8; ++r) acc[r] = win[r] * xv;

        if (j > 0) {
            const float* hp = states + (size_t)(g - 1) * RR;
            _Float16* sh = h16 + ((j - 1) & 1) * RR;
            // First pass: 4 coalesced dword poll loads per thread.
            float v0 = __hip_atomic_load(hp + tid,
                                         __ATOMIC_RELAXED, __HIP_MEMORY_SCOPE_AGENT);
            float v1 = __hip_atomic_load(hp + tid + 512,
                                         __ATOMIC_RELAXED, __HIP_MEMORY_SCOPE_AGENT);
            float v2 = __hip_atomic_load(hp + tid + 1024,
                                         __ATOMIC_RELAXED, __HIP_MEMORY_SCOPE_AGENT);
            float v3 = __hip_atomic_load(hp + tid + 1536,
                                         __ATOMIC_RELAXED, __HIP_MEMORY_SCOPE_AGENT);
            // Parity-range readiness: accept only my chunk's bias range.
            for (;;) {
                const bool r0 = fabsf(v0 - bias) <= 1.25f;
                const bool r1 = fabsf(v1 - bias) <= 1.25f;
                const bool r2 = fabsf(v2 - bias) <= 1.25f;
                const bool r3 = fabsf(v3 - bias) <= 1.25f;
                if (r0 && r1 && r2 && r3) break;
                if (!r0) v0 = __hip_atomic_load(hp + tid,
                                __ATOMIC_RELAXED, __HIP_MEMORY_SCOPE_AGENT);
                if (!r1) v1 = __hip_atomic_load(hp + tid + 512,
                                __ATOMIC_RELAXED, __HIP_MEMORY_SCOPE_AGENT);
                if (!r2) v2 = __hip_atomic_load(hp + tid + 1024,
                                __ATOMIC_RELAXED, __HIP_MEMORY_SCOPE_AGENT);
                if (!r3) v3 = __hip_atomic_load(hp + tid + 1536,
                                __ATOMIC_RELAXED, __HIP_MEMORY_SCOPE_AGENT);
            }
            // Publish f16-rounded biased h only (4 cvt + 4 ds_write_b16).
            sh[tid]        = (_Float16)v0;
            sh[tid + 512]  = (_Float16)v1;
            sh[tid + 1024] = (_Float16)v2;
            sh[tid + 1536] = (_Float16)v3;
            __syncthreads();           // the ONLY barrier per round

            // Consume: 8x ds_read_b64 (h f16) + 32x ds_read_b64 (W f16).
            // ALL rows via v_dot2_f32_f16: rows 0..3 vs register-packed W,
            // rows 4..7 vs LDS W. 16 fdot2 per m-step.
            const uint2* sq16 = (const uint2*)sh;
#pragma unroll
            for (int m = 0; m < 8; ++m) {
                const uint2 qh = sq16[lane + 64 * m];
                const h2v qlo = __builtin_bit_cast(h2v, qh.x);
                const h2v qhi = __builtin_bit_cast(h2v, qh.y);
#pragma unroll
                for (int r = 0; r < 4; ++r) {
                    const float4 wp = wq16[r][m >> 1];
                    const float pw0 = (m & 1) ? wp.z : wp.x;
                    const float pw1 = (m & 1) ? wp.w : wp.y;
                    acc[r] = __builtin_amdgcn_fdot2(
                        __builtin_bit_cast(h2v, pw0), qlo, acc[r], false);
                    acc[r] = __builtin_amdgcn_fdot2(
                        __builtin_bit_cast(h2v, pw1), qhi, acc[r], false);
                }
#pragma unroll
                for (int rr = 0; rr < 4; ++rr) {
                    const uint2 wp = wl2[(size_t)(wrow + rr) * 512 + lane + 64 * m];
                    acc[4 + rr] = __builtin_amdgcn_fdot2(
                        __builtin_bit_cast(h2v, wp.x), qlo, acc[4 + rr], false);
                    acc[4 + rr] = __builtin_amdgcn_fdot2(
                        __builtin_bit_cast(h2v, wp.y), qhi, acc[4 + rr], false);
                }
            }
        }

        // Reduce 8 rows: 3 fold stages + 3-level butterfly (10 shfls).
        {
            const float u01 = ((lane & 1) ? acc[1] : acc[0])
                            + __shfl_xor((lane & 1) ? acc[0] : acc[1], 1, 64);
            const float u23 = ((lane & 1) ? acc[3] : acc[2])
                            + __shfl_xor((lane & 1) ? acc[2] : acc[3], 1, 64);
            const float u45 = ((lane & 1) ? acc[5] : acc[4])
                            + __shfl_xor((lane & 1) ? acc[4] : acc[5], 1, 64);
            const float u67 = ((lane & 1) ? acc[7] : acc[6])
                            + __shfl_xor((lane & 1) ? acc[6] : acc[7], 1, 64);
            const float v03 = ((lane & 2) ? u23 : u01)
                            + __shfl_xor((lane & 2) ? u01 : u23, 2, 64);
            const float v47 = ((lane & 2) ? u67 : u45)
                            + __shfl_xor((lane & 2) ? u45 : u67, 2, 64);
            float a = ((lane & 4) ? v47 : v03)
                    + __shfl_xor((lane & 4) ? v03 : v47, 4, 64);
#pragma unroll
            for (int off = 8; off <= 32; off <<= 1)
                a += __shfl_xor(a, off, 64);
            // Bias-fold correction (only when biased h was consumed)
            if (j > 0) a -= twred;
            // tanh + leaky update for row R0 + (lane&7)
            float u = fminf(fmaxf(a, -20.f), 20.f);
            const float e  = __expf(2.f * u);
            const float th = (e - 1.f) / (e + 1.f);
            const float hn = 0.5f * hold + 0.5f * th;
            hold = hn;
            if (lane < 8)
                __hip_atomic_store(&states[(size_t)g * RR + R0 + lane], hn + bias,
                                   __ATOMIC_RELAXED, __HIP_MEMORY_SCOPE_AGENT);
        }
    }
}

// ---------------------------------------------------------------------------
// rowsum of fc1_w rows: rs[h] = sum_r fc1_w[h][r]
// ---------------------------------------------------------------------------
__global__ void k_rowsum(const float* __restrict__ fc1w, float* __restrict__ rs)
{
    const int h = blockIdx.x;
    const int tid = threadIdx.x;
    float a = 0.f;
    for (int r = tid; r < RR; r += 256) a += fc1w[(size_t)h * RR + r];
#pragma unroll
    for (int off = 1; off <= 32; off <<= 1) a += __shfl_xor(a, off, 64);
    __shared__ float red[4];
    if ((tid & 63) == 0) red[tid >> 6] = a;
    __syncthreads();
    if (tid == 0) rs[h] = red[0] + red[1] + red[2] + red[3];
}

// ---------------------------------------------------------------------------
// Mt[r][o] = sum_h fc2_w[o][h] * fc1_w[h][r]   (o padded to 64, zeros)
// ---------------------------------------------------------------------------
__global__ void k_mt(const float* __restrict__ fc1w,
                     const float* __restrict__ fc2w,
                     float* __restrict__ Mt)
{
    __shared__ float w2[OO][HH + 1];
    const int o = threadIdx.x;         // 64
    const int r = blockIdx.x;          // 2048
    for (int i = o; i < OO * HH; i += 64) w2[i / HH][i % HH] = fc2w[i];
    __syncthreads();
    float a = 0.f;
    if (o < OO) {
        for (int h = 0; h < HH; ++h)
            a += w2[o][h] * fc1w[(size_t)h * RR + r];
    }
    Mt[r * OP + o] = a;
}

// ---------------------------------------------------------------------------
// c2b[o] = fc2_b[o] + sum_h fc2_w[o][h]*fc1_b[h];  rm[o] = sum_h fc2w*rs[h]
// ---------------------------------------------------------------------------
__global__ void k_cc(const float* __restrict__ fc2w,
                     const float* __restrict__ fc2b,
                     const float* __restrict__ fc1b,
                     const float* __restrict__ rs,
                     float* __restrict__ c2b,
                     float* __restrict__ rm)
{
    const int o = threadIdx.x;  // 64
    float a = 0.f, b = 0.f;
    if (o < OO) {
        for (int h = 0; h < HH; ++h) {
            a += fc2w[o * HH + h] * fc1b[h];
            b += fc2w[o * HH + h] * rs[h];
        }
        a += fc2b[o];
    }
    c2b[o] = a;
    rm[o]  = b;
}

// ---------------------------------------------------------------------------
// out[t][o] = sum_r Mt[r][o] * states_biased[t][r] + c2b[o] - bias_t*rm[o]
// Chunk boundaries (2104 + 2040k) are NOT %16-aligned -> bias per element.
// ---------------------------------------------------------------------------
__global__ __launch_bounds__(256)
void out_kernel(const float* __restrict__ sb,
                const float* __restrict__ Mt,
                const float* __restrict__ c2b,
                const float* __restrict__ rm,
                float* __restrict__ out)
{
    const int tid = threadIdx.x;
    const int o   = tid & 63;
    const int tl  = tid >> 6;          // 0..3
    const int t0  = blockIdx.x * TT;
    float acc[4] = {0.f, 0.f, 0.f, 0.f};
    const float* s0 = sb + (size_t)t0 * RR;

    for (int r = 0; r < RR; r += 4) {
        float4 sv0 = *(const float4*)(s0 + (size_t)(tl + 0)  * RR + r);
        float4 sv1 = *(const float4*)(s0 + (size_t)(tl + 4)  * RR + r);
        float4 sv2 = *(const float4*)(s0 + (size_t)(tl + 8)  * RR + r);
        float4 sv3 = *(const float4*)(s0 + (size_t)(tl + 12) * RR + r);
        float m0 = Mt[(r + 0) * OP + o];
        float m1 = Mt[(r + 1) * OP + o];
        float m2 = Mt[(r + 2) * OP + o];
        float m3 = Mt[(r + 3) * OP + o];
        acc[0] += m0 * sv0.x + m1 * sv0.y + m2 * sv0.z + m3 * sv0.w;
        acc[1] += m0 * sv1.x + m1 * sv1.y + m2 * sv1.z + m3 * sv1.w;
        acc[2] += m0 * sv2.x + m1 * sv2.y + m2 * sv2.z + m3 * sv2.w;
        acc[3] += m0 * sv3.x + m1 * sv3.y + m2 * sv3.z + m3 * sv3.w;
    }
    if (o < OO) {
        const float cb = c2b[o];
        const float rv = rm[o];
#pragma unroll
        for (int m = 0; m < 4; ++m) {
            const int t = t0 + tl + 4 * m;
            const int ch = (t < C0LEN) ? 0 : (1 + (t - C0LEN) / CLEN);
            const float bias = (ch & 1) ? 6.0f : 2.0f;
            out[(size_t)t * OO + o] = acc[m] + cb - bias * rv;
        }
    }
}

extern "C" void kernel_launch(void* const* d_in, const int* in_sizes, int n_in,
                              void* d_out, int out_size, void* d_ws, size_t ws_size,
                              hipStream_t stream)
{
    const float* x    = (const float*)d_in[0];
    const float* Win  = (const float*)d_in[1];
    const float* W    = (const float*)d_in[2];
    const float* fc1w = (const float*)d_in[3];
    const float* fc1b = (const float*)d_in[4];
    const float* fc2w = (const float*)d_in[5];
    const float* fc2b = (const float*)d_in[6];
    float* out = (float*)d_out;

    if (ws_size < WS_NEED) return;

    char*  ws     = (char*)d_ws;
    float* states = (float*)ws;
    float* Mt     = (float*)(ws + MT_OFF);
    float* c2b    = (float*)(ws + C2B_OFF);
    float* rm     = (float*)(ws + RM_OFF);
    float* rs     = (float*)(ws + RS_OFF);

    // Raise the dynamic-LDS cap once (not a stream op; graph-capture safe).
    static bool attr_done = false;
    if (!attr_done) {
        hipFuncSetAttribute(reinterpret_cast<const void*>(scan_kernel),
                            hipFuncAttributeMaxDynamicSharedMemorySize,
                            SMEM_BYTES);
        attr_done = true;
    }

    // Sentinel init: 0.0f is outside both bias ranges -> "not ready".
    hipMemsetAsync(states, 0, STATES_BYTES, stream);

    k_rowsum<<<HH, 256, 0, stream>>>(fc1w, rs);
    k_mt<<<RR, 64, 0, stream>>>(fc1w, fc2w, Mt);
    k_cc<<<1, 64, 0, stream>>>(fc2w, fc2b, fc1b, rs, c2b, rm);

    scan_kernel<<<NBLK, NTHR, SMEM_BYTES, stream>>>(x, Win, W, states);

    out_kernel<<<SS / TT, 256, 0, stream>>>(states, Mt, c2b, rm, out);
}